// Round 10
// baseline (333.306 us; speedup 1.0000x reference)
//
#include <hip/hip_runtime.h>

#define HW 3136
#define NPOS 12845056   // 16*256*3136

__device__ __forceinline__ unsigned fkey(float f) {
  unsigned u = __float_as_uint(f);
  return (u & 0x80000000u) ? ~u : (u | 0x80000000u);
}
__device__ __forceinline__ float funkey(unsigned u) {
  return __uint_as_float((u & 0x80000000u) ? (u & 0x7FFFFFFFu) : ~u);
}
__device__ __forceinline__ float spikef(float x) {
  return fminf(fmaxf(rintf(x), 0.0f), 4.0f);
}
__device__ __forceinline__ float rdlane(float v, int src) {
  return __int_as_float(__builtin_amdgcn_readlane(__float_as_int(v), src));
}

// ---------------- Kernel 1: transposes + audio pre-projection + init ----------------
// w1t: [k 256][j 128]   w2t: [k2 128][j2 64]
__global__ __launch_bounds__(256) void prep_kernel(
    const float* __restrict__ audio, const float* __restrict__ w1,
    const float* __restrict__ b1, const float* __restrict__ w2,
    float* __restrict__ a_pre, float* __restrict__ w1t,
    float* __restrict__ w2t, float* __restrict__ pool,
    unsigned* __restrict__ mm)
{
  __shared__ float au[256];
  const int bx = blockIdx.x, t = threadIdx.x;
  if (bx < 128) {                       // w1 visual half -> w1t[k][j]
    int idx = bx * 256 + t;             // 32768
    int c = idx >> 7, j = idx & 127;
    w1t[idx] = w1[j * 512 + c];
  } else if (bx < 160) {                // w2 -> w2t[k][j2]
    int idx = (bx - 128) * 256 + t;     // 8192
    int k = idx >> 6, j2 = idx & 63;
    w2t[idx] = w2[j2 * 128 + k];
  } else if (bx < 176) {                // a_pre[b][j] = b1[j] + w1[j][256:512].audio[b]
    int b = bx - 160;
    au[t] = audio[b * 256 + t];
    __syncthreads();
    int w = t >> 6, l = t & 63;
    float a0 = au[l], a1 = au[l + 64], a2 = au[l + 128], a3 = au[l + 192];
    for (int jj = 0; jj < 32; ++jj) {
      int j = w * 32 + jj;
      const float* row = w1 + j * 512 + 256;
      float s = row[l] * a0 + row[l + 64] * a1 + row[l + 128] * a2 + row[l + 192] * a3;
      #pragma unroll
      for (int off = 32; off; off >>= 1) s += __shfl_xor(s, off);
      if (l == 0) a_pre[b * 128 + j] = s + b1[j];
    }
  } else {
    for (int i = t; i < 4096; i += 256) pool[i] = 0.0f;
    if (t == 0) { mm[0] = 0xFFFFFFFFu; mm[1] = 0u; }
  }
}

// ---------------- Kernel 2: fused MLP + mi + pooling ----------------
// Round-16: LDS-BANDWIDTH theory (fits all 9 rounds: broadcast ds_read_b128
// still writes back 1KB -> round 9 moved 4.25B/FMA = 6.8GB LDS = 99us).
// GEMM1: 8x8 per-lane register tiles (1B/FMA, 4x less LDS traffic; DS-bound
// cap 67%). 512 thr = 8 waves = 2 j-halves x 4-way k-split per 32k chunk;
// partials combined via 3 lane-linear LDS rounds. GEMM2: w2 in 16 VGPRs,
// v_readlane broadcast (uniform lane idx), lane=pos, wave=j2-octet, no
// combine, VALU-bound. Grid 49x16 (no tail). ~51KB LDS, launch_bounds(512,4)
// -> 128 VGPR cap, 16 waves/CU.
__global__ __launch_bounds__(512, 4) void mlp_kernel(
    const float* __restrict__ fm, const float* __restrict__ w1t,
    const float* __restrict__ w2t, const float* __restrict__ b2,
    const float* __restrict__ w3, const float* __restrict__ b3,
    const float* __restrict__ g1, const float* __restrict__ be1,
    const float* __restrict__ g2, const float* __restrict__ be2,
    const float* __restrict__ a_pre, float* __restrict__ mi_out,
    float* __restrict__ pool, unsigned* __restrict__ mm)
{
  // floats: A dbuf [0,4096) = 2x[32k][64pos]; B dbuf [4096,12288) = 2x[32k][128j]
  // combine scratch [0,8192) = [jw][32 a2][64 l][2]; then h1f[128][64] at [0,8192)
  __shared__ __align__(16) float smem[12288];   // 48 KB
  __shared__ float red[16][64];                 // 4 KB

  const int b  = blockIdx.y;
  const int s0 = blockIdx.x * 64;
  const int t  = threadIdx.x;
  const int l  = t & 63;
  const int wv = __builtin_amdgcn_readfirstlane(t >> 6);   // 0..7, uniform
  const int jw = wv & 1;          // j-half (GEMM1)
  const int kq = wv >> 1;         // k-quarter (GEMM1)
  const int p8 = l >> 3;          // pos-octet: pos = p8*8 + ii
  const int j8 = l & 7;           // j-octet:   j = jw*64 + j8*8 + jj

  const float* fmblk = fm + (size_t)b * 256 * HW + s0;

  auto stage = [&](int ch, int bd) {
    {   // A: [32k][64pos] 8KB; wave wv stages rows 4wv..4wv+3 (1 issue)
      const float* g = fmblk + (size_t)(ch * 32 + wv * 4 + (l >> 4)) * HW
                       + (l & 15) * 4;
      float* d = smem + bd * 2048 + wv * 256;
      __builtin_amdgcn_global_load_lds(
          (const __attribute__((address_space(1))) void*)g,
          (__attribute__((address_space(3))) void*)d, 16, 0, 0);
    }
    #pragma unroll
    for (int i = 0; i < 2; ++i) {   // B: [32k][128j] 16KB; rows 4wv..4wv+3
      const float* g = w1t + (size_t)(ch * 32 + wv * 4 + i * 2 + (l >> 5)) * 128
                       + (l & 31) * 4;
      float* d = smem + 4096 + bd * 4096 + (wv * 4 + i * 2) * 128;
      __builtin_amdgcn_global_load_lds(
          (const __attribute__((address_space(1))) void*)g,
          (__attribute__((address_space(3))) void*)d, 16, 0, 0);
    }
  };

  // ---- GEMM1: acc[ii][jj] over this wave's k-slices ----
  float acc[8][8];
  #pragma unroll
  for (int ii = 0; ii < 8; ++ii)
    #pragma unroll
    for (int jj = 0; jj < 8; ++jj) acc[ii][jj] = 0.f;

  stage(0, 0);
  __syncthreads();
  #pragma unroll 1
  for (int ch = 0; ch < 8; ++ch) {
    if (ch < 7) stage(ch + 1, (ch + 1) & 1);
    const float* Ab = smem + (ch & 1) * 2048 + kq * 8 * 64 + p8 * 8;
    const float* Bb = smem + 4096 + (ch & 1) * 4096 + kq * 8 * 128 + jw * 64 + j8 * 8;
    #pragma unroll
    for (int k = 0; k < 8; ++k) {
      float4 a0 = *(const float4*)(Ab + k * 64);
      float4 a1 = *(const float4*)(Ab + k * 64 + 4);
      float4 b0 = *(const float4*)(Bb + k * 128);
      float4 b1 = *(const float4*)(Bb + k * 128 + 4);
      float av[8] = {a0.x, a0.y, a0.z, a0.w, a1.x, a1.y, a1.z, a1.w};
      float bv[8] = {b0.x, b0.y, b0.z, b0.w, b1.x, b1.y, b1.z, b1.w};
      #pragma unroll
      for (int ii = 0; ii < 8; ++ii)
        #pragma unroll
        for (int jj = 0; jj < 8; ++jj)
          acc[ii][jj] = fmaf(av[ii], bv[jj], acc[ii][jj]);
    }
    __syncthreads();
  }

  // ---- w2 -> 16 VGPRs (lane m holds w2[2m]/w2[2m+1], this wave's j2-octet) ----
  float4 xw0, xw1, xw2, xw3;
  {
    const float* wp = w2t + (2 * l) * 64 + wv * 8;
    xw0 = *(const float4*)(wp);
    xw1 = *(const float4*)(wp + 4);
    xw2 = *(const float4*)(wp + 64);
    xw3 = *(const float4*)(wp + 68);
  }

  // ---- combine k-split partials: kq0 += kq1 + (kq2 += kq3) ----
  float* scr = smem;   // [jw][32 a2][64 l][2]
  auto wr = [&]() {
    float* p = scr + jw * 4096 + l * 2;
    #pragma unroll
    for (int ii = 0; ii < 8; ++ii)
      #pragma unroll
      for (int q = 0; q < 4; ++q)
        *(float2*)(p + (ii * 4 + q) * 128) = make_float2(acc[ii][2*q], acc[ii][2*q+1]);
  };
  auto ad = [&]() {
    const float* p = scr + jw * 4096 + l * 2;
    #pragma unroll
    for (int ii = 0; ii < 8; ++ii)
      #pragma unroll
      for (int q = 0; q < 4; ++q) {
        float2 v = *(const float2*)(p + (ii * 4 + q) * 128);
        acc[ii][2*q] += v.x; acc[ii][2*q+1] += v.y;
      }
  };
  if (kq == 1) wr();
  __syncthreads();
  if (kq == 0) ad();
  __syncthreads();
  if (kq == 3) wr();
  __syncthreads();
  if (kq == 2) ad();
  __syncthreads();
  if (kq == 2) wr();
  __syncthreads();
  if (kq == 0) ad();

  // ---- bias + LN1 + spike -> h1f (kq==0 waves hold full sums) ----
  float mu[8], inv[8];
  if (kq == 0) {
    const float* ap = a_pre + b * 128 + jw * 64 + j8 * 8;
    float4 A0 = *(const float4*)(ap), A1 = *(const float4*)(ap + 4);
    float av[8] = {A0.x, A0.y, A0.z, A0.w, A1.x, A1.y, A1.z, A1.w};
    float s[8];
    #pragma unroll
    for (int ii = 0; ii < 8; ++ii) {
      float v = 0.f;
      #pragma unroll
      for (int jj = 0; jj < 8; ++jj) { acc[ii][jj] += av[jj]; v += acc[ii][jj]; }
      v += __shfl_xor(v, 1); v += __shfl_xor(v, 2); v += __shfl_xor(v, 4);
      s[ii] = v;
    }
    if (j8 == 0) {
      *(float4*)&red[jw][p8 * 8]     = make_float4(s[0], s[1], s[2], s[3]);
      *(float4*)&red[jw][p8 * 8 + 4] = make_float4(s[4], s[5], s[6], s[7]);
    }
  }
  __syncthreads();
  if (kq == 0) {
    float4 r00 = *(const float4*)&red[0][p8 * 8];
    float4 r01 = *(const float4*)&red[0][p8 * 8 + 4];
    float4 r10 = *(const float4*)&red[1][p8 * 8];
    float4 r11 = *(const float4*)&red[1][p8 * 8 + 4];
    mu[0] = (r00.x + r10.x) * (1.0f/128.0f); mu[1] = (r00.y + r10.y) * (1.0f/128.0f);
    mu[2] = (r00.z + r10.z) * (1.0f/128.0f); mu[3] = (r00.w + r10.w) * (1.0f/128.0f);
    mu[4] = (r01.x + r11.x) * (1.0f/128.0f); mu[5] = (r01.y + r11.y) * (1.0f/128.0f);
    mu[6] = (r01.z + r11.z) * (1.0f/128.0f); mu[7] = (r01.w + r11.w) * (1.0f/128.0f);
    float s[8];
    #pragma unroll
    for (int ii = 0; ii < 8; ++ii) {
      float v = 0.f;
      #pragma unroll
      for (int jj = 0; jj < 8; ++jj) { float d = acc[ii][jj] - mu[ii]; v = fmaf(d, d, v); }
      v += __shfl_xor(v, 1); v += __shfl_xor(v, 2); v += __shfl_xor(v, 4);
      s[ii] = v;
    }
    if (j8 == 0) {
      *(float4*)&red[2 + jw][p8 * 8]     = make_float4(s[0], s[1], s[2], s[3]);
      *(float4*)&red[2 + jw][p8 * 8 + 4] = make_float4(s[4], s[5], s[6], s[7]);
    }
  }
  __syncthreads();
  if (kq == 0) {
    float4 v00 = *(const float4*)&red[2][p8 * 8];
    float4 v01 = *(const float4*)&red[2][p8 * 8 + 4];
    float4 v10 = *(const float4*)&red[3][p8 * 8];
    float4 v11 = *(const float4*)&red[3][p8 * 8 + 4];
    inv[0] = 1.0f / sqrtf((v00.x + v10.x) * (1.0f/128.0f) + 1e-5f);
    inv[1] = 1.0f / sqrtf((v00.y + v10.y) * (1.0f/128.0f) + 1e-5f);
    inv[2] = 1.0f / sqrtf((v00.z + v10.z) * (1.0f/128.0f) + 1e-5f);
    inv[3] = 1.0f / sqrtf((v00.w + v10.w) * (1.0f/128.0f) + 1e-5f);
    inv[4] = 1.0f / sqrtf((v01.x + v11.x) * (1.0f/128.0f) + 1e-5f);
    inv[5] = 1.0f / sqrtf((v01.y + v11.y) * (1.0f/128.0f) + 1e-5f);
    inv[6] = 1.0f / sqrtf((v01.z + v11.z) * (1.0f/128.0f) + 1e-5f);
    inv[7] = 1.0f / sqrtf((v01.w + v11.w) * (1.0f/128.0f) + 1e-5f);
    const float* gp = g1  + jw * 64 + j8 * 8;
    const float* bp = be1 + jw * 64 + j8 * 8;
    float4 G0 = *(const float4*)(gp), G1 = *(const float4*)(gp + 4);
    float4 B0 = *(const float4*)(bp), B1 = *(const float4*)(bp + 4);
    float gv[8] = {G0.x, G0.y, G0.z, G0.w, G1.x, G1.y, G1.z, G1.w};
    float bv[8] = {B0.x, B0.y, B0.z, B0.w, B1.x, B1.y, B1.z, B1.w};
    #pragma unroll
    for (int jj = 0; jj < 8; ++jj) {
      float4 h0, h1v;
      h0.x  = spikef((acc[0][jj] - mu[0]) * inv[0] * gv[jj] + bv[jj]);
      h0.y  = spikef((acc[1][jj] - mu[1]) * inv[1] * gv[jj] + bv[jj]);
      h0.z  = spikef((acc[2][jj] - mu[2]) * inv[2] * gv[jj] + bv[jj]);
      h0.w  = spikef((acc[3][jj] - mu[3]) * inv[3] * gv[jj] + bv[jj]);
      h1v.x = spikef((acc[4][jj] - mu[4]) * inv[4] * gv[jj] + bv[jj]);
      h1v.y = spikef((acc[5][jj] - mu[5]) * inv[5] * gv[jj] + bv[jj]);
      h1v.z = spikef((acc[6][jj] - mu[6]) * inv[6] * gv[jj] + bv[jj]);
      h1v.w = spikef((acc[7][jj] - mu[7]) * inv[7] * gv[jj] + bv[jj]);
      float* hp = smem + (jw * 64 + j8 * 8 + jj) * 64 + p8 * 8;
      *(float4*)(hp) = h0;
      *(float4*)(hp + 4) = h1v;
    }
  }
  __syncthreads();                       // h1f[128][64] resident at smem[0,8192)

  // ---- GEMM2: lane = pos, wave = j2-octet (wv), K2=128, w2 via readlane ----
  float a2[8];
  #pragma unroll
  for (int j = 0; j < 8; ++j) a2[j] = 0.f;
  {
    const float* hp = smem + l;
    #pragma unroll 4
    for (int m = 0; m < 64; ++m) {       // k2 = 2m, 2m+1; src lane = m (uniform)
      float he = hp[(2 * m) * 64];
      float ho = hp[(2 * m + 1) * 64];
      a2[0] = fmaf(ho, rdlane(xw2.x, m), fmaf(he, rdlane(xw0.x, m), a2[0]));
      a2[1] = fmaf(ho, rdlane(xw2.y, m), fmaf(he, rdlane(xw0.y, m), a2[1]));
      a2[2] = fmaf(ho, rdlane(xw2.z, m), fmaf(he, rdlane(xw0.z, m), a2[2]));
      a2[3] = fmaf(ho, rdlane(xw2.w, m), fmaf(he, rdlane(xw0.w, m), a2[3]));
      a2[4] = fmaf(ho, rdlane(xw3.x, m), fmaf(he, rdlane(xw1.x, m), a2[4]));
      a2[5] = fmaf(ho, rdlane(xw3.y, m), fmaf(he, rdlane(xw1.y, m), a2[5]));
      a2[6] = fmaf(ho, rdlane(xw3.z, m), fmaf(he, rdlane(xw1.z, m), a2[6]));
      a2[7] = fmaf(ho, rdlane(xw3.w, m), fmaf(he, rdlane(xw1.w, m), a2[7]));
    }
  }
  {   // + b2 (this wave's j2-octet)
    float4 b20 = *(const float4*)(b2 + wv * 8);
    float4 b21 = *(const float4*)(b2 + wv * 8 + 4);
    a2[0] += b20.x; a2[1] += b20.y; a2[2] += b20.z; a2[3] += b20.w;
    a2[4] += b21.x; a2[5] += b21.y; a2[6] += b21.z; a2[7] += b21.w;
  }

  // ---- LN2 over j2=64 (8 in-lane + 8-wave cross via red) + spike + mi ----
  {
    float s = 0.f;
    #pragma unroll
    for (int j = 0; j < 8; ++j) s += a2[j];
    red[wv][l] = s;
  }
  __syncthreads();
  float mu2;
  {
    float s = 0.f;
    #pragma unroll
    for (int q = 0; q < 8; ++q) s += red[q][l];
    mu2 = s * (1.0f/64.0f);
    float s2 = 0.f;
    #pragma unroll
    for (int j = 0; j < 8; ++j) { float d = a2[j] - mu2; s2 = fmaf(d, d, s2); }
    red[8 + wv][l] = s2;
  }
  __syncthreads();
  float mip;
  {
    float s2 = 0.f;
    #pragma unroll
    for (int q = 0; q < 8; ++q) s2 += red[8 + q][l];
    float inv2 = 1.0f / sqrtf(s2 * (1.0f/64.0f) + 1e-5f);
    float4 g20 = *(const float4*)(g2 + wv * 8);
    float4 g21 = *(const float4*)(g2 + wv * 8 + 4);
    float4 e20 = *(const float4*)(be2 + wv * 8);
    float4 e21 = *(const float4*)(be2 + wv * 8 + 4);
    float4 w30 = *(const float4*)(w3 + wv * 8);
    float4 w31 = *(const float4*)(w3 + wv * 8 + 4);
    float gv[8] = {g20.x, g20.y, g20.z, g20.w, g21.x, g21.y, g21.z, g21.w};
    float ev[8] = {e20.x, e20.y, e20.z, e20.w, e21.x, e21.y, e21.z, e21.w};
    float wv3[8] = {w30.x, w30.y, w30.z, w30.w, w31.x, w31.y, w31.z, w31.w};
    float p = 0.f;
    #pragma unroll
    for (int j = 0; j < 8; ++j) {
      float sp = spikef((a2[j] - mu2) * inv2 * gv[j] + ev[j]);
      p = fmaf(sp, wv3[j], p);
    }
    mip = p;
  }
  __syncthreads();                 // rows 0-15 reads done before row reuse
  red[wv][l] = mip;
  __syncthreads();
  float mi = b3[0];
  #pragma unroll
  for (int q = 0; q < 8; ++q) mi += red[q][l];   // mi for pos = s0 + l

  if (wv == 0) {
    mi_out[b * HW + s0 + l] = mi;                // coalesced 256B
    float mn = mi, mx = mi;
    #pragma unroll
    for (int off = 32; off; off >>= 1) {
      mn = fminf(mn, __shfl_xor(mn, off));
      mx = fmaxf(mx, __shfl_xor(mx, off));
    }
    if (l == 0) {
      unsigned kmn = fkey(mn), kmx = fkey(mx);
      volatile unsigned* vmm = (volatile unsigned*)mm;
      if (kmn < vmm[0]) atomicMin(&mm[0], kmn);
      if (kmx > vmm[1]) atomicMax(&mm[1], kmx);
    }
  }

  // ---- pooling: pool[b][c] += sum_pos mi[pos]*fm[b][c][pos], 32 c/wave ----
  {
    const float* fp2 = fmblk + l + (size_t)(wv << 5) * HW;
    #pragma unroll 4
    for (int ci = 0; ci < 32; ++ci) {
      float v = fp2[(size_t)ci * HW] * mi;
      #pragma unroll
      for (int off = 32; off; off >>= 1) v += __shfl_xor(v, off);
      if (l == 0) atomicAdd(&pool[b * 256 + (wv << 5) + ci], v);
    }
  }
}

// ---------------- Kernel 3: projection + LN + spike -> channel scale ----------------
__global__ __launch_bounds__(256) void scale_kernel(
    const float* __restrict__ pool, const float* __restrict__ pw,
    const float* __restrict__ pb, const float* __restrict__ pg,
    const float* __restrict__ pbeta, float* __restrict__ scale,
    const unsigned* __restrict__ mm, float* __restrict__ gpar)
{
  __shared__ float pl[256];
  __shared__ float xsh[256];
  __shared__ float rs[4], rs2[4];
  int b = blockIdx.x, t = threadIdx.x;
  pl[t] = pool[b*256 + t];
  __syncthreads();
  int w = t >> 6, l = t & 63;
  float p0 = pl[l], p1 = pl[l+64], p2 = pl[l+128], p3 = pl[l+192];
  for (int jj = 0; jj < 64; ++jj) {
    int j = w*64 + jj;
    const float* row = pw + j*256;
    float s = row[l]*p0 + row[l+64]*p1 + row[l+128]*p2 + row[l+192]*p3;
    #pragma unroll
    for (int off = 32; off; off >>= 1) s += __shfl_xor(s, off);
    if (l == 0) xsh[j] = s;
  }
  __syncthreads();
  float x = xsh[t] + pb[t];
  float s = x;
  #pragma unroll
  for (int off = 32; off; off >>= 1) s += __shfl_xor(s, off);
  if (l == 0) rs[w] = s;
  __syncthreads();
  float mu = (rs[0]+rs[1]+rs[2]+rs[3]) * (1.0f/256.0f);
  float d = x - mu;
  float s2 = d*d;
  #pragma unroll
  for (int off = 32; off; off >>= 1) s2 += __shfl_xor(s2, off);
  if (l == 0) rs2[w] = s2;
  __syncthreads();
  float var = (rs2[0]+rs2[1]+rs2[2]+rs2[3]) * (1.0f/256.0f);
  float v = d / sqrtf(var + 1e-5f) * pg[t] + pbeta[t];
  scale[b*256 + t] = spikef(v);
  if (b == 0 && t == 0) {
    float mn = funkey(mm[0]), mx = funkey(mm[1]);
    gpar[0] = mn;
    gpar[1] = mx - mn + 1e-6f;
  }
}

// ---------------- Kernel 4: fusion map + normalized mi map ----------------
__global__ __launch_bounds__(256) void fuse_kernel(
    const float4* __restrict__ fm4, const float* __restrict__ scale,
    const float4* __restrict__ mi4, const float* __restrict__ gpar,
    float4* __restrict__ out4, float4* __restrict__ mi4out)
{
  const int c = blockIdx.x, b = blockIdx.y, t = threadIdx.x;
  if (c < 256) {
    float s = scale[b * 256 + c];
    size_t base = ((size_t)b * 256 + c) * 784;
    #pragma unroll
    for (int i = 0; i < 3; ++i) {
      int idx = t + i * 256;
      float4 v = fm4[base + idx];
      out4[base + idx] = make_float4(v.x*s, v.y*s, v.z*s, v.w*s);
    }
    int idx = t + 768;
    if (idx < 784) {
      float4 v = fm4[base + idx];
      out4[base + idx] = make_float4(v.x*s, v.y*s, v.z*s, v.w*s);
    }
  } else {
    float gmin = gpar[0], den = gpar[1];
    size_t base = (size_t)b * 784;
    #pragma unroll
    for (int i = 0; i < 3; ++i) {
      int idx = t + i * 256;
      float4 v = mi4[base + idx];
      mi4out[base + idx] = make_float4((v.x-gmin)/den, (v.y-gmin)/den,
                                       (v.z-gmin)/den, (v.w-gmin)/den);
    }
    int idx = t + 768;
    if (idx < 784) {
      float4 v = mi4[base + idx];
      mi4out[base + idx] = make_float4((v.x-gmin)/den, (v.y-gmin)/den,
                                       (v.z-gmin)/den, (v.w-gmin)/den);
    }
  }
}

extern "C" void kernel_launch(void* const* d_in, const int* in_sizes, int n_in,
                              void* d_out, int out_size, void* d_ws, size_t ws_size,
                              hipStream_t stream)
{
  const float* fm    = (const float*)d_in[0];
  const float* audio = (const float*)d_in[1];
  const float* w1    = (const float*)d_in[2];
  const float* b1    = (const float*)d_in[3];
  const float* g1    = (const float*)d_in[4];
  const float* be1   = (const float*)d_in[5];
  const float* w2    = (const float*)d_in[6];
  const float* b2    = (const float*)d_in[7];
  const float* g2    = (const float*)d_in[8];
  const float* be2   = (const float*)d_in[9];
  const float* w3    = (const float*)d_in[10];
  const float* b3    = (const float*)d_in[11];
  const float* pw    = (const float*)d_in[12];
  const float* pb    = (const float*)d_in[13];
  const float* pg    = (const float*)d_in[14];
  const float* pbeta = (const float*)d_in[15];

  float* ws    = (float*)d_ws;
  float* a_pre = ws;               // 2048 floats
  float* pool  = ws + 2048;        // 4096
  float* scale = ws + 6144;        // 4096
  float* mi    = ws + 10240;       // 50176 (16B aligned)
  float* w1t   = ws + 60416;       // 32768  [k][j]
  float* w2t   = ws + 93184;       // 8192   [k][j2]
  unsigned* mm = (unsigned*)(ws + 101376);  // 2 keys
  float* gpar  = ws + 101378;      // gmin, denom

  float* out    = (float*)d_out;
  float* mi4out = out + NPOS;

  prep_kernel<<<177, 256, 0, stream>>>(audio, w1, b1, w2, a_pre, w1t, w2t,
                                       pool, mm);
  mlp_kernel<<<dim3(49, 16), 512, 0, stream>>>(fm, w1t, w2t, b2, w3, b3,
                                               g1, be1, g2, be2,
                                               a_pre, mi, pool, mm);
  scale_kernel<<<16, 256, 0, stream>>>(pool, pw, pb, pg, pbeta, scale, mm, gpar);
  fuse_kernel<<<dim3(257, 16), 256, 0, stream>>>((const float4*)fm, scale,
                                                 (const float4*)mi, gpar,
                                                 (float4*)out, (float4*)mi4out);
}